// Round 13
// baseline (2633.357 us; speedup 1.0000x reference)
//
#include <hip/hip_runtime.h>
#include <hip/hip_bf16.h>
#include <math.h>

typedef unsigned short u16;
typedef unsigned long long u64;
typedef __attribute__((ext_vector_type(8))) short short8;
typedef __attribute__((ext_vector_type(4))) float f32x4;
typedef __attribute__((ext_vector_type(2))) _Float16 half2v;

static __device__ __forceinline__ u16 f2b(float x) {
  __hip_bfloat16 h = __float2bfloat16(x);
  return *reinterpret_cast<u16*>(&h);
}
static __device__ __forceinline__ float b2f(u16 u) {
  unsigned int v = ((unsigned int)u) << 16;
  float f;
  __builtin_memcpy(&f, &v, 4);
  return f;
}
static __device__ __forceinline__ u16 f2h(float x) {
  _Float16 h = (_Float16)x;
  u16 u;
  __builtin_memcpy(&u, &h, 2);
  return u;
}
static __device__ __forceinline__ float dot2(unsigned w, unsigned h, float acc) {
  half2v a, b;
  __builtin_memcpy(&a, &w, 4);
  __builtin_memcpy(&b, &h, 4);
#if __has_builtin(__builtin_amdgcn_fdot2)
  return __builtin_amdgcn_fdot2(a, b, acc, false);
#else
  return acc + (float)a[0] * (float)b[0] + (float)a[1] * (float)b[1];
#endif
}

// agent-scope relaxed (cache-bypassing) accessors
static __device__ __forceinline__ float aldf(const float* p) {
  return __hip_atomic_load(const_cast<float*>(p), __ATOMIC_RELAXED, __HIP_MEMORY_SCOPE_AGENT);
}
static __device__ __forceinline__ void astf(float* p, float v) {
  __hip_atomic_store(p, v, __ATOMIC_RELAXED, __HIP_MEMORY_SCOPE_AGENT);
}
static __device__ __forceinline__ u64 ald8(const u64* p) {
  return __hip_atomic_load(const_cast<u64*>(p), __ATOMIC_RELAXED, __HIP_MEMORY_SCOPE_AGENT);
}
static __device__ __forceinline__ void ast32(unsigned* p, unsigned v) {
  __hip_atomic_store(p, v, __ATOMIC_RELAXED, __HIP_MEMORY_SCOPE_AGENT);
}

// ---------------- conversion kernels ----------------

__global__ void cvt_flat(const float* __restrict__ s, u16* __restrict__ d, long n) {
  long i = ((long)blockIdx.x * 256 + threadIdx.x) * 4;
  long stride = (long)gridDim.x * 1024;
  for (; i < n; i += stride) {
    float4 v = *(const float4*)(s + i);
    ushort4 o;
    o.x = f2b(v.x); o.y = f2b(v.y); o.z = f2b(v.z); o.w = f2b(v.w);
    *(ushort4*)(d + i) = o;
  }
}

// pack pairs of f32 -> u32 of 2 f16 (flat)
__global__ void cvt_packh(const float* __restrict__ s, unsigned* __restrict__ d, long npairs) {
  long i = (long)blockIdx.x * 256 + threadIdx.x;
  long step = (long)gridDim.x * 256;
  for (; i < npairs; i += step) {
    float2 v = *(const float2*)(s + 2 * i);
    d[i] = (unsigned)f2h(v.x) | ((unsigned)f2h(v.y) << 16);
  }
}

__global__ void cvt_strided(const float* __restrict__ s, u16* __restrict__ d,
                            long total, int lshift, long sstride, long soff) {
  long i = (long)blockIdx.x * 256 + threadIdx.x;
  long step = (long)gridDim.x * 256;
  long mask = (1L << lshift) - 1;
  for (; i < total; i += step) {
    long r = i >> lshift;
    long c = i & mask;
    d[i] = f2b(s[r * sstride + soff + c]);
  }
}

__global__ void cvt_x(const float* __restrict__ gt, u16* __restrict__ d) {
  long idx = (long)blockIdx.x * 256 + threadIdx.x;
  if (idx >= 1024L * 512) return;
  long m = idx >> 9;
  int k = (int)(idx & 511);
  if (m < 992) {
    int tt = (int)(m >> 5), b = (int)(m & 31);
    d[idx] = f2b(gt[((long)b * 32 + tt) * 512 + k]);
  } else {
    d[idx] = 0;
  }
}

// ---------------- generic MFMA GEMM: C = A(M,K) * B(N,K)^T ----------------
template<int EPI>
__global__ __launch_bounds__(256)
void gemm_bt(const u16* __restrict__ A, const u16* __restrict__ B,
             void* __restrict__ C0,
             const float* __restrict__ bias, const float* __restrict__ pw,
             int M, int N, int K) {
  __shared__ u16 As[4096];
  __shared__ u16 Bs[4096];
  const int tid = threadIdx.x;
  const int lane = tid & 63, wid = tid >> 6;

  int gx = gridDim.x, gy = gridDim.y;
  int orig = blockIdx.y * gx + blockIdx.x;
  int G = gx < 8 ? gx : 8;
  int ng = gx / G;
  int full = ng * G * gy;
  int ct, rt;
  if (orig < full) {
    int grp = orig / (G * gy), rem = orig % (G * gy);
    ct = grp * G + rem % G;
    rt = rem / G;
  } else {
    int Gt = gx - ng * G;
    int rem = orig - full;
    ct = ng * G + rem % Gt;
    rt = rem / Gt;
  }
  const long row0 = (long)rt * 128;
  const long col0 = (long)ct * 128;

  const int wm = (wid >> 1) * 64, wn = (wid & 1) * 64;
  const int fr = lane & 15, fq = lane >> 4;
  const int sr = wid * 16 + (lane >> 2);
  const int sc = (lane & 3) * 8;

  const u16* Ag0 = A + (row0 + sr) * (long)K + sc;
  const u16* Ag1 = Ag0 + 64 * (long)K;
  const u16* Bg0 = B + (col0 + sr) * (long)K + sc;
  const u16* Bg1 = Bg0 + 64 * (long)K;

  u16* AsW0 = &As[wid * 512];
  u16* AsW1 = &As[2048 + wid * 512];
  u16* BsW0 = &Bs[wid * 512];
  u16* BsW1 = &Bs[2048 + wid * 512];

  f32x4 acc[4][4];
#pragma unroll
  for (int i = 0; i < 4; ++i)
#pragma unroll
    for (int j = 0; j < 4; ++j) acc[i][j] = {0.f, 0.f, 0.f, 0.f};

  for (int k0 = 0; k0 < K; k0 += 32) {
    __builtin_amdgcn_global_load_lds((const __attribute__((address_space(1))) void*)(Ag0 + k0),
                                     (__attribute__((address_space(3))) void*)AsW0, 16, 0, 0);
    __builtin_amdgcn_global_load_lds((const __attribute__((address_space(1))) void*)(Ag1 + k0),
                                     (__attribute__((address_space(3))) void*)AsW1, 16, 0, 0);
    __builtin_amdgcn_global_load_lds((const __attribute__((address_space(1))) void*)(Bg0 + k0),
                                     (__attribute__((address_space(3))) void*)BsW0, 16, 0, 0);
    __builtin_amdgcn_global_load_lds((const __attribute__((address_space(1))) void*)(Bg1 + k0),
                                     (__attribute__((address_space(3))) void*)BsW1, 16, 0, 0);
    __syncthreads();
    short8 af[4], bfv[4];
#pragma unroll
    for (int i = 0; i < 4; ++i) af[i] = *(const short8*)&As[(wm + i * 16 + fr) * 32 + fq * 8];
#pragma unroll
    for (int i = 0; i < 4; ++i) bfv[i] = *(const short8*)&Bs[(wn + i * 16 + fr) * 32 + fq * 8];
#pragma unroll
    for (int i = 0; i < 4; ++i)
#pragma unroll
      for (int j = 0; j < 4; ++j)
        acc[i][j] = __builtin_amdgcn_mfma_f32_16x16x32_bf16(af[i], bfv[j], acc[i][j], 0, 0, 0);
    __syncthreads();
  }

#pragma unroll
  for (int i = 0; i < 4; ++i)
#pragma unroll
    for (int j = 0; j < 4; ++j)
#pragma unroll
      for (int q = 0; q < 4; ++q) {
        long gr = row0 + wm + i * 16 + fq * 4 + q;
        long gc = col0 + wn + j * 16 + fr;
        float v = acc[i][j][q];
        if constexpr (EPI == 0) {
          ((u16*)C0)[gr * (long)N + gc] = f2b(v);
        } else if constexpr (EPI == 1) {
          ((u16*)C0)[gr * (long)N + gc] = f2b(tanhf(v + bias[gc]) * pw[gc]);
        } else if constexpr (EPI == 2) {
          if (gr < M) ((float*)C0)[gr * (long)N + gc] = v + bias[gc];
        } else {  // EPI == 3
          if (gr < M) {
            long bb = gr & 31, tt = gr >> 5;
            float o = v + bias[gc];
            __builtin_nontemporal_store(o, &((float*)C0)[(bb * 31 + tt) * (long)N + gc]);
          }
        }
      }
}

// ---------------- persistent recurrence kernel (XCD-aligned partitions) ----------------
// 256 blocks x 1024 threads, cooperative. r6/r12 relaxed barrier + UC passing.
// Phase A (gates GEMV, f16 dot2): block = (rowg = blk&7, bA = blk>>3).
//   Rows [rowg*416, +416) for ONE b. Blocks sharing an XCD (RR heuristic
//   XCD = blk%8) share the SAME 0.83 MB f16 weight slice -> L2-resident; and
//   replication-free chip-wide (6.8 MB/step reads) regardless of mapping.
//   h: f16-packed hG32[bA] (2 KB) staged UC->LDS (34-stride pad, conflict-
//   free); thread (akc=tid&15, rl=tid>>4) holds 64-k slice in 32 u32 regs,
//   ~7 rows each, 16-lane shfl reduce, UC store gates.
// Phase B (attn + GRU): block = (b = blk&31, jc = blk>>5) -> per-XCD FWb
//   footprint 3.1 MB + wvf 256 KB (L2-fit). Code = r12 phase B; h written
//   f16-packed via shfl-pair.
__global__ __launch_bounds__(1024)
void persist(const unsigned* __restrict__ WcatH, const float* __restrict__ bcat,
             const u16* __restrict__ wvfb, const u16* __restrict__ FWb,
             const float* __restrict__ GX, const float* __restrict__ pbv,
             const float* __restrict__ h0,
             unsigned* __restrict__ hG32, float* __restrict__ gates,
             u16* __restrict__ Hbuf, unsigned* __restrict__ cnt) {
  const int tid = threadIdx.x;
  const int blk = blockIdx.x;
  const int R0 = (blk & 7) * 416, bA = blk >> 3;  // phase A role
  const int b = blk & 31, jc = blk >> 5;          // phase B role

  __shared__ unsigned hl32[16 * 34];  // padded: bank(akc*34) = 2*akc, distinct
  __shared__ float uhl[256];
  __shared__ float part[1024];
  __shared__ float attnv[128];
  __shared__ float gmp[3][1024];
  __shared__ float hl2[128];          // persistent f32 h slice (b, jc)

  const float pb0 = pbv[0];
  if (tid < 128) hl2[tid] = h0[b * 1024 + jc * 128 + tid];

  auto xbar = [&](unsigned target) {
    __syncthreads();
    if (tid == 0) {
      __hip_atomic_fetch_add(cnt, 1u, __ATOMIC_RELAXED, __HIP_MEMORY_SCOPE_AGENT);
      while (__hip_atomic_load(cnt, __ATOMIC_RELAXED, __HIP_MEMORY_SCOPE_AGENT) < target) {
        __builtin_amdgcn_s_sleep(2);
      }
    }
    __syncthreads();
  };

  for (int t = 0; t < 31; ++t) {
    // ===== phase A: gates GEMV (f16 dot2, replication-free) =====
    if (tid < 256) {
      u64 v = ald8((const u64*)hG32 + (long)bA * 256 + tid);
      unsigned lo = (unsigned)v, hi = (unsigned)(v >> 32);
      int k2 = tid * 2;
      hl32[(k2 >> 5) * 34 + (k2 & 31)] = lo;
      k2++;
      hl32[(k2 >> 5) * 34 + (k2 & 31)] = hi;
    }
    __syncthreads();
    {
      const int akc = tid & 15, rl = tid >> 4;
      unsigned hreg[32];
#pragma unroll
      for (int j = 0; j < 32; ++j) hreg[j] = hl32[akc * 34 + j];
#pragma unroll
      for (int i = 0; i < 7; ++i) {
        if (i < 6 || rl < 32) {
          int rr = i * 64 + rl;
          const unsigned* wr = WcatH + (long)(R0 + rr) * 512 + akc * 32;
          float acc = 0.f;
#pragma unroll
          for (int j = 0; j < 8; ++j) {
            uint4 w4 = *(const uint4*)(wr + j * 4);
            acc = dot2(w4.x, hreg[4 * j], acc);
            acc = dot2(w4.y, hreg[4 * j + 1], acc);
            acc = dot2(w4.z, hreg[4 * j + 2], acc);
            acc = dot2(w4.w, hreg[4 * j + 3], acc);
          }
          acc += __shfl_xor(acc, 1);
          acc += __shfl_xor(acc, 2);
          acc += __shfl_xor(acc, 4);
          acc += __shfl_xor(acc, 8);
          if (akc == 0) astf(gates + (long)bA * 3328 + R0 + rr, acc);
        }
      }
    }
    xbar(256u * (2 * t + 1));

    // ===== phase B: attention + GRU (r12 structure; b=blk&31, jc=blk>>5) =====
    if (tid < 128) {
      u64 v = ald8((const u64*)(gates + (long)b * 3328 + tid * 2));
      float2 f2v;
      __builtin_memcpy(&f2v, &v, 8);
      uhl[tid * 2] = tanhf(f2v.x + bcat[tid * 2]);
      uhl[tid * 2 + 1] = tanhf(f2v.y + bcat[tid * 2 + 1]);
    }
    __syncthreads();
    {
      const int s = tid & 127, q = tid >> 7;  // q in 0..7, 32 dims each
      const u16* wr = wvfb + ((long)(b * 128 + s)) * 256 + q * 32;
      const float* uq = &uhl[q * 32];
      float p = 0.f;
#pragma unroll
      for (int d = 0; d < 32; d += 8) {
        short8 wv = *(const short8*)(wr + d);
#pragma unroll
        for (int e = 0; e < 8; ++e) p += b2f((u16)wv[e]) * uq[d + e];
      }
      part[tid] = p;
    }
    __syncthreads();
    if (tid < 128) {
      float s8 = pb0;
#pragma unroll
      for (int j = 0; j < 8; ++j) s8 += part[tid + 128 * j];
      attnv[tid] = s8;
    }
    __syncthreads();
    if (tid < 64) {
      float m = fmaxf(attnv[tid], attnv[tid + 64]);
#pragma unroll
      for (int o = 32; o; o >>= 1) m = fmaxf(m, __shfl_xor(m, o));
      float e0 = expf(attnv[tid] - m), e1 = expf(attnv[tid + 64] - m);
      float s2 = e0 + e1;
#pragma unroll
      for (int o = 32; o; o >>= 1) s2 += __shfl_xor(s2, o);
      float inv = 1.f / s2;
      attnv[tid] = e0 * inv;
      attnv[tid + 64] = e1 * inv;
    }
    __syncthreads();
    {
      const int ml = tid & 127, sh = tid >> 7;  // sh in 0..7, 16 s each
      const int col = jc * 128 + ml;
      float g0 = 0.f, g1 = 0.f, g2 = 0.f;
      const u16* fw = FWb + ((long)(b * 128 + sh * 16)) * 3072 + col;
#pragma unroll 4
      for (int s = 0; s < 16; ++s) {
        float a = attnv[sh * 16 + s];
        g0 += a * b2f(fw[0]);
        g1 += a * b2f(fw[1024]);
        g2 += a * b2f(fw[2048]);
        fw += 3072;
      }
      gmp[0][tid] = g0; gmp[1][tid] = g1; gmp[2][tid] = g2;
    }
    __syncthreads();
    if (tid < 128) {
      const int m = jc * 128 + tid;
      float gm0 = 0.f, gm1 = 0.f, gm2 = 0.f;
#pragma unroll
      for (int j = 0; j < 8; ++j) {
        gm0 += gmp[0][tid + 128 * j];
        gm1 += gmp[1][tid + 128 * j];
        gm2 += gmp[2][tid + 128 * j];
      }
      float gh0 = aldf(gates + (long)b * 3328 + 256 + m) + bcat[256 + m];
      float gh1 = aldf(gates + (long)b * 3328 + 1280 + m) + bcat[1280 + m];
      float gh2 = aldf(gates + (long)b * 3328 + 2304 + m) + bcat[2304 + m];
      const long gxo = ((long)t * 32 + b) * 3072;
      float xr = GX[gxo + m] + gm0;
      float xz = GX[gxo + 1024 + m] + gm1;
      float xn = GX[gxo + 2048 + m] + gm2;
      float r = 1.f / (1.f + expf(-(xr + gh0)));
      float z = 1.f / (1.f + expf(-(xz + gh1)));
      float n = tanhf(xn + r * gh2);
      float h2 = (1.f - z) * n + z * hl2[tid];
      hl2[tid] = h2;
      Hbuf[((long)t * 32 + b) * 1024 + m] = f2b(h2);
      float hp = __shfl_xor(h2, 1);
      if ((tid & 1) == 0) {
        unsigned pk = (unsigned)f2h(h2) | ((unsigned)f2h(hp) << 16);
        ast32(hG32 + (long)b * 512 + jc * 64 + (tid >> 1), pk);
      }
    }
    xbar(256u * (2 * t + 2));
  }
}

// ---------------- launcher ----------------

extern "C" void kernel_launch(void* const* d_in, const int* in_sizes, int n_in,
                              void* d_out, int out_size, void* d_ws, size_t ws_size,
                              hipStream_t stream) {
  const float* f    = (const float*)d_in[0];
  const float* h0   = (const float*)d_in[1];
  const float* gt   = (const float*)d_in[2];
  const float* U_w  = (const float*)d_in[4];
  const float* U_b  = (const float*)d_in[5];
  const float* V_w  = (const float*)d_in[6];
  const float* V_b  = (const float*)d_in[7];
  const float* P_w  = (const float*)d_in[8];
  const float* P_b  = (const float*)d_in[9];
  const float* W_ih = (const float*)d_in[10];
  const float* b_ih = (const float*)d_in[11];
  const float* W_hh = (const float*)d_in[12];
  const float* b_hh = (const float*)d_in[13];
  const float* dw   = (const float*)d_in[14];
  const float* db   = (const float*)d_in[15];

  char* w = (char*)d_ws;
  auto alloc = [&](size_t bytes) { char* p = w; w += (bytes + 255) & ~255ULL; return p; };

  u16*      fbf   = (u16*)alloc(4096L * 1024 * 2);
  u16*      VwB   = (u16*)alloc(256L * 1024 * 2);
  unsigned* WcatH = (unsigned*)alloc(3328L * 512 * 4);  // f16-packed [U_w; W_hh]
  u16*      WxB   = (u16*)alloc(3072L * 512 * 2);
  u16*      WmB   = (u16*)alloc(3072L * 1024 * 2);
  u16*      dwB   = (u16*)alloc(32000L * 1024 * 2);
  u16*      Xb    = (u16*)alloc(1024L * 512 * 2);
  u16*      wvfb  = (u16*)alloc(4096L * 256 * 2);
  float*    GX    = (float*)alloc(1024L * 3072 * 4);
  u16*      FWb   = (u16*)alloc(4096L * 3072 * 2);
  unsigned* hG32  = (unsigned*)alloc(32L * 512 * 4);    // f16-packed h state
  float*    gates = (float*)alloc(32L * 3328 * 4);
  u16*      Hbuf  = (u16*)alloc(1024L * 1024 * 2);
  float*    bcat  = (float*)alloc(3328L * 4);
  unsigned* cnt   = (unsigned*)alloc(256);

  auto cvg = [](long n) { long g = (n + 1023) / 1024; return (int)(g > 2048 ? 2048 : g); };

  cvt_flat<<<cvg(4194304), 256, 0, stream>>>(f, fbf, 4194304);
  cvt_flat<<<cvg(262144), 256, 0, stream>>>(V_w, VwB, 262144);
  cvt_packh<<<512, 256, 0, stream>>>(U_w, WcatH, 131072);
  cvt_packh<<<2048, 256, 0, stream>>>(W_hh, WcatH + 131072, 1572864);
  cvt_packh<<<64, 256, 0, stream>>>(h0, hG32, 16384);
  cvt_strided<<<2048, 256, 0, stream>>>(W_ih, WxB, 3072L * 512, 9, 1536, 0);
  cvt_strided<<<2048, 256, 0, stream>>>(W_ih, WmB, 3072L * 1024, 10, 1536, 512);
  cvt_flat<<<cvg(32768000), 256, 0, stream>>>(dw, dwB, 32768000);
  cvt_x<<<2048, 256, 0, stream>>>(gt, Xb);
  hipMemcpyAsync(bcat, U_b, 256 * 4, hipMemcpyDeviceToDevice, stream);
  hipMemcpyAsync(bcat + 256, b_hh, 3072 * 4, hipMemcpyDeviceToDevice, stream);
  hipMemsetAsync(cnt, 0, 4, stream);

  // loop-invariant GEMMs (bf16)
  gemm_bt<1><<<dim3(2, 32), 256, 0, stream>>>(fbf, VwB, wvfb, V_b, P_w, 4096, 256, 1024);
  gemm_bt<2><<<dim3(24, 8), 256, 0, stream>>>(Xb, WxB, GX, b_ih, nullptr, 992, 3072, 512);
  gemm_bt<0><<<dim3(24, 32), 256, 0, stream>>>(fbf, WmB, FWb, nullptr, nullptr, 4096, 3072, 1024);

  // full recurrence: persistent kernel, XCD-aligned partitions + f16 dot2 gates
  {
    void* ka[] = {(void*)&WcatH, (void*)&bcat, (void*)&wvfb, (void*)&FWb,
                  (void*)&GX,    (void*)&P_b,  (void*)&h0,   (void*)&hG32,
                  (void*)&gates, (void*)&Hbuf, (void*)&cnt};
    hipLaunchCooperativeKernel((void*)persist, dim3(256), dim3(1024), ka, 0, stream);
  }

  // logits
  gemm_bt<3><<<dim3(250, 8), 256, 0, stream>>>(Hbuf, dwB, (float*)d_out, db, nullptr,
                                               992, 32000, 1024);
}

// Round 14
// 2405.696 us; speedup vs baseline: 1.0946x; 1.0946x over previous
//
#include <hip/hip_runtime.h>
#include <hip/hip_bf16.h>
#include <math.h>

typedef unsigned short u16;
typedef unsigned long long u64;
typedef __attribute__((ext_vector_type(8))) short short8;
typedef __attribute__((ext_vector_type(4))) float f32x4;
typedef __attribute__((ext_vector_type(2))) _Float16 half2v;

static __device__ __forceinline__ u16 f2b(float x) {
  __hip_bfloat16 h = __float2bfloat16(x);
  return *reinterpret_cast<u16*>(&h);
}
static __device__ __forceinline__ float b2f(u16 u) {
  unsigned int v = ((unsigned int)u) << 16;
  float f;
  __builtin_memcpy(&f, &v, 4);
  return f;
}
static __device__ __forceinline__ u16 f2h(float x) {
  _Float16 h = (_Float16)x;
  u16 u;
  __builtin_memcpy(&u, &h, 2);
  return u;
}
static __device__ __forceinline__ float dot2(unsigned w, unsigned h, float acc) {
  half2v a, b;
  __builtin_memcpy(&a, &w, 4);
  __builtin_memcpy(&b, &h, 4);
#if __has_builtin(__builtin_amdgcn_fdot2)
  return __builtin_amdgcn_fdot2(a, b, acc, false);
#else
  return acc + (float)a[0] * (float)b[0] + (float)a[1] * (float)b[1];
#endif
}

// agent-scope relaxed (cache-bypassing) accessors
static __device__ __forceinline__ float aldf(const float* p) {
  return __hip_atomic_load(const_cast<float*>(p), __ATOMIC_RELAXED, __HIP_MEMORY_SCOPE_AGENT);
}
static __device__ __forceinline__ void astf(float* p, float v) {
  __hip_atomic_store(p, v, __ATOMIC_RELAXED, __HIP_MEMORY_SCOPE_AGENT);
}
static __device__ __forceinline__ u64 ald8(const u64* p) {
  return __hip_atomic_load(const_cast<u64*>(p), __ATOMIC_RELAXED, __HIP_MEMORY_SCOPE_AGENT);
}
static __device__ __forceinline__ void ast32(unsigned* p, unsigned v) {
  __hip_atomic_store(p, v, __ATOMIC_RELAXED, __HIP_MEMORY_SCOPE_AGENT);
}

// ---------------- conversion kernels ----------------

__global__ void cvt_flat(const float* __restrict__ s, u16* __restrict__ d, long n) {
  long i = ((long)blockIdx.x * 256 + threadIdx.x) * 4;
  long stride = (long)gridDim.x * 1024;
  for (; i < n; i += stride) {
    float4 v = *(const float4*)(s + i);
    ushort4 o;
    o.x = f2b(v.x); o.y = f2b(v.y); o.z = f2b(v.z); o.w = f2b(v.w);
    *(ushort4*)(d + i) = o;
  }
}

// pack pairs of f32 -> u32 of 2 f16 (flat)
__global__ void cvt_packh(const float* __restrict__ s, unsigned* __restrict__ d, long npairs) {
  long i = (long)blockIdx.x * 256 + threadIdx.x;
  long step = (long)gridDim.x * 256;
  for (; i < npairs; i += step) {
    float2 v = *(const float2*)(s + 2 * i);
    d[i] = (unsigned)f2h(v.x) | ((unsigned)f2h(v.y) << 16);
  }
}

__global__ void cvt_strided(const float* __restrict__ s, u16* __restrict__ d,
                            long total, int lshift, long sstride, long soff) {
  long i = (long)blockIdx.x * 256 + threadIdx.x;
  long step = (long)gridDim.x * 256;
  long mask = (1L << lshift) - 1;
  for (; i < total; i += step) {
    long r = i >> lshift;
    long c = i & mask;
    d[i] = f2b(s[r * sstride + soff + c]);
  }
}

__global__ void cvt_x(const float* __restrict__ gt, u16* __restrict__ d) {
  long idx = (long)blockIdx.x * 256 + threadIdx.x;
  if (idx >= 1024L * 512) return;
  long m = idx >> 9;
  int k = (int)(idx & 511);
  if (m < 992) {
    int tt = (int)(m >> 5), b = (int)(m & 31);
    d[idx] = f2b(gt[((long)b * 32 + tt) * 512 + k]);
  } else {
    d[idx] = 0;
  }
}

// ---------------- generic MFMA GEMM: C = A(M,K) * B(N,K)^T ----------------
template<int EPI>
__global__ __launch_bounds__(256)
void gemm_bt(const u16* __restrict__ A, const u16* __restrict__ B,
             void* __restrict__ C0,
             const float* __restrict__ bias, const float* __restrict__ pw,
             int M, int N, int K) {
  __shared__ u16 As[4096];
  __shared__ u16 Bs[4096];
  const int tid = threadIdx.x;
  const int lane = tid & 63, wid = tid >> 6;

  int gx = gridDim.x, gy = gridDim.y;
  int orig = blockIdx.y * gx + blockIdx.x;
  int G = gx < 8 ? gx : 8;
  int ng = gx / G;
  int full = ng * G * gy;
  int ct, rt;
  if (orig < full) {
    int grp = orig / (G * gy), rem = orig % (G * gy);
    ct = grp * G + rem % G;
    rt = rem / G;
  } else {
    int Gt = gx - ng * G;
    int rem = orig - full;
    ct = ng * G + rem % Gt;
    rt = rem / Gt;
  }
  const long row0 = (long)rt * 128;
  const long col0 = (long)ct * 128;

  const int wm = (wid >> 1) * 64, wn = (wid & 1) * 64;
  const int fr = lane & 15, fq = lane >> 4;
  const int sr = wid * 16 + (lane >> 2);
  const int sc = (lane & 3) * 8;

  const u16* Ag0 = A + (row0 + sr) * (long)K + sc;
  const u16* Ag1 = Ag0 + 64 * (long)K;
  const u16* Bg0 = B + (col0 + sr) * (long)K + sc;
  const u16* Bg1 = Bg0 + 64 * (long)K;

  u16* AsW0 = &As[wid * 512];
  u16* AsW1 = &As[2048 + wid * 512];
  u16* BsW0 = &Bs[wid * 512];
  u16* BsW1 = &Bs[2048 + wid * 512];

  f32x4 acc[4][4];
#pragma unroll
  for (int i = 0; i < 4; ++i)
#pragma unroll
    for (int j = 0; j < 4; ++j) acc[i][j] = {0.f, 0.f, 0.f, 0.f};

  for (int k0 = 0; k0 < K; k0 += 32) {
    __builtin_amdgcn_global_load_lds((const __attribute__((address_space(1))) void*)(Ag0 + k0),
                                     (__attribute__((address_space(3))) void*)AsW0, 16, 0, 0);
    __builtin_amdgcn_global_load_lds((const __attribute__((address_space(1))) void*)(Ag1 + k0),
                                     (__attribute__((address_space(3))) void*)AsW1, 16, 0, 0);
    __builtin_amdgcn_global_load_lds((const __attribute__((address_space(1))) void*)(Bg0 + k0),
                                     (__attribute__((address_space(3))) void*)BsW0, 16, 0, 0);
    __builtin_amdgcn_global_load_lds((const __attribute__((address_space(1))) void*)(Bg1 + k0),
                                     (__attribute__((address_space(3))) void*)BsW1, 16, 0, 0);
    __syncthreads();
    short8 af[4], bfv[4];
#pragma unroll
    for (int i = 0; i < 4; ++i) af[i] = *(const short8*)&As[(wm + i * 16 + fr) * 32 + fq * 8];
#pragma unroll
    for (int i = 0; i < 4; ++i) bfv[i] = *(const short8*)&Bs[(wn + i * 16 + fr) * 32 + fq * 8];
#pragma unroll
    for (int i = 0; i < 4; ++i)
#pragma unroll
      for (int j = 0; j < 4; ++j)
        acc[i][j] = __builtin_amdgcn_mfma_f32_16x16x32_bf16(af[i], bfv[j], acc[i][j], 0, 0, 0);
    __syncthreads();
  }

#pragma unroll
  for (int i = 0; i < 4; ++i)
#pragma unroll
    for (int j = 0; j < 4; ++j)
#pragma unroll
      for (int q = 0; q < 4; ++q) {
        long gr = row0 + wm + i * 16 + fq * 4 + q;
        long gc = col0 + wn + j * 16 + fr;
        float v = acc[i][j][q];
        if constexpr (EPI == 0) {
          ((u16*)C0)[gr * (long)N + gc] = f2b(v);
        } else if constexpr (EPI == 1) {
          ((u16*)C0)[gr * (long)N + gc] = f2b(tanhf(v + bias[gc]) * pw[gc]);
        } else if constexpr (EPI == 2) {
          if (gr < M) ((float*)C0)[gr * (long)N + gc] = v + bias[gc];
        } else {  // EPI == 3
          if (gr < M) {
            long bb = gr & 31, tt = gr >> 5;
            float o = v + bias[gc];
            __builtin_nontemporal_store(o, &((float*)C0)[(bb * 31 + tt) * (long)N + gc]);
          }
        }
      }
}

// ---------------- persistent recurrence kernel (CHUNKED-XCD-aligned) ----------------
// 256 blocks x 1024 threads, cooperative. r6/r12 relaxed barrier + fixed UC
// buffers (step-unique staging is pathological -- r8/r9/r10 lesson).
// Mapping hypothesis from r12/r13 counter-fit: XCD = blk>>5 (chunked; 1
// block/CU, linear). Partitions aligned to it:
// Phase A (gates GEMV, f16 dot2): R0 = (blk>>5)*416, bA = blk&31.
//   The 32 blocks of one XCD share ONE 0.83 MB f16 weight slice (L2-resident);
//   replication-free chip-wide. h via UC from fixed hG32.
// Phase B (attn + GRU): b = (blk>>5)*4 + (blk&3), jc = (blk&31)>>2.
//   Per XCD: 4 b's -> wvf 256 KB + FWb slice 3.1 MB (L2-fit with phase A's
//   0.83 MB; total ~4.2 MB).
__global__ __launch_bounds__(1024)
void persist(const unsigned* __restrict__ WcatH, const float* __restrict__ bcat,
             const u16* __restrict__ wvfb, const u16* __restrict__ FWb,
             const float* __restrict__ GX, const float* __restrict__ pbv,
             const float* __restrict__ h0,
             unsigned* __restrict__ hG32, float* __restrict__ gates,
             u16* __restrict__ Hbuf, unsigned* __restrict__ cnt) {
  const int tid = threadIdx.x;
  const int blk = blockIdx.x;
  const int R0 = (blk >> 5) * 416, bA = blk & 31;        // phase A role
  const int b = (blk >> 5) * 4 + (blk & 3);              // phase B role
  const int jc = (blk & 31) >> 2;

  __shared__ unsigned hl32[16 * 34];  // padded: bank(akc*34) = 2*akc, distinct
  __shared__ float uhl[256];
  __shared__ float part[1024];
  __shared__ float attnv[128];
  __shared__ float gmp[3][1024];
  __shared__ float hl2[128];          // persistent f32 h slice (b, jc)

  const float pb0 = pbv[0];
  if (tid < 128) hl2[tid] = h0[b * 1024 + jc * 128 + tid];

  auto xbar = [&](unsigned target) {
    __syncthreads();
    if (tid == 0) {
      __hip_atomic_fetch_add(cnt, 1u, __ATOMIC_RELAXED, __HIP_MEMORY_SCOPE_AGENT);
      while (__hip_atomic_load(cnt, __ATOMIC_RELAXED, __HIP_MEMORY_SCOPE_AGENT) < target) {
        __builtin_amdgcn_s_sleep(2);
      }
    }
    __syncthreads();
  };

  for (int t = 0; t < 31; ++t) {
    // ===== phase A: gates GEMV (f16 dot2, replication-free, XCD-shared rows) =====
    if (tid < 256) {
      u64 v = ald8((const u64*)hG32 + (long)bA * 256 + tid);
      unsigned lo = (unsigned)v, hi = (unsigned)(v >> 32);
      int k2 = tid * 2;
      hl32[(k2 >> 5) * 34 + (k2 & 31)] = lo;
      k2++;
      hl32[(k2 >> 5) * 34 + (k2 & 31)] = hi;
    }
    __syncthreads();
    {
      const int akc = tid & 15, rl = tid >> 4;
      unsigned hreg[32];
#pragma unroll
      for (int j = 0; j < 32; ++j) hreg[j] = hl32[akc * 34 + j];
#pragma unroll
      for (int i = 0; i < 7; ++i) {
        if (i < 6 || rl < 32) {
          int rr = i * 64 + rl;
          const unsigned* wr = WcatH + (long)(R0 + rr) * 512 + akc * 32;
          float acc = 0.f;
#pragma unroll
          for (int j = 0; j < 8; ++j) {
            uint4 w4 = *(const uint4*)(wr + j * 4);
            acc = dot2(w4.x, hreg[4 * j], acc);
            acc = dot2(w4.y, hreg[4 * j + 1], acc);
            acc = dot2(w4.z, hreg[4 * j + 2], acc);
            acc = dot2(w4.w, hreg[4 * j + 3], acc);
          }
          acc += __shfl_xor(acc, 1);
          acc += __shfl_xor(acc, 2);
          acc += __shfl_xor(acc, 4);
          acc += __shfl_xor(acc, 8);
          if (akc == 0) astf(gates + (long)bA * 3328 + R0 + rr, acc);
        }
      }
    }
    xbar(256u * (2 * t + 1));

    // ===== phase B: attention + GRU (r12 structure; chunked-aligned b/jc) =====
    if (tid < 128) {
      u64 v = ald8((const u64*)(gates + (long)b * 3328 + tid * 2));
      float2 f2v;
      __builtin_memcpy(&f2v, &v, 8);
      uhl[tid * 2] = tanhf(f2v.x + bcat[tid * 2]);
      uhl[tid * 2 + 1] = tanhf(f2v.y + bcat[tid * 2 + 1]);
    }
    __syncthreads();
    {
      const int s = tid & 127, q = tid >> 7;  // q in 0..7, 32 dims each
      const u16* wr = wvfb + ((long)(b * 128 + s)) * 256 + q * 32;
      const float* uq = &uhl[q * 32];
      float p = 0.f;
#pragma unroll
      for (int d = 0; d < 32; d += 8) {
        short8 wv = *(const short8*)(wr + d);
#pragma unroll
        for (int e = 0; e < 8; ++e) p += b2f((u16)wv[e]) * uq[d + e];
      }
      part[tid] = p;
    }
    __syncthreads();
    if (tid < 128) {
      float s8 = pb0;
#pragma unroll
      for (int j = 0; j < 8; ++j) s8 += part[tid + 128 * j];
      attnv[tid] = s8;
    }
    __syncthreads();
    if (tid < 64) {
      float m = fmaxf(attnv[tid], attnv[tid + 64]);
#pragma unroll
      for (int o = 32; o; o >>= 1) m = fmaxf(m, __shfl_xor(m, o));
      float e0 = expf(attnv[tid] - m), e1 = expf(attnv[tid + 64] - m);
      float s2 = e0 + e1;
#pragma unroll
      for (int o = 32; o; o >>= 1) s2 += __shfl_xor(s2, o);
      float inv = 1.f / s2;
      attnv[tid] = e0 * inv;
      attnv[tid + 64] = e1 * inv;
    }
    __syncthreads();
    {
      const int ml = tid & 127, sh = tid >> 7;  // sh in 0..7, 16 s each
      const int col = jc * 128 + ml;
      float g0 = 0.f, g1 = 0.f, g2 = 0.f;
      const u16* fw = FWb + ((long)(b * 128 + sh * 16)) * 3072 + col;
#pragma unroll 4
      for (int s = 0; s < 16; ++s) {
        float a = attnv[sh * 16 + s];
        g0 += a * b2f(fw[0]);
        g1 += a * b2f(fw[1024]);
        g2 += a * b2f(fw[2048]);
        fw += 3072;
      }
      gmp[0][tid] = g0; gmp[1][tid] = g1; gmp[2][tid] = g2;
    }
    __syncthreads();
    if (tid < 128) {
      const int m = jc * 128 + tid;
      float gm0 = 0.f, gm1 = 0.f, gm2 = 0.f;
#pragma unroll
      for (int j = 0; j < 8; ++j) {
        gm0 += gmp[0][tid + 128 * j];
        gm1 += gmp[1][tid + 128 * j];
        gm2 += gmp[2][tid + 128 * j];
      }
      float gh0 = aldf(gates + (long)b * 3328 + 256 + m) + bcat[256 + m];
      float gh1 = aldf(gates + (long)b * 3328 + 1280 + m) + bcat[1280 + m];
      float gh2 = aldf(gates + (long)b * 3328 + 2304 + m) + bcat[2304 + m];
      const long gxo = ((long)t * 32 + b) * 3072;
      float xr = GX[gxo + m] + gm0;
      float xz = GX[gxo + 1024 + m] + gm1;
      float xn = GX[gxo + 2048 + m] + gm2;
      float r = 1.f / (1.f + expf(-(xr + gh0)));
      float z = 1.f / (1.f + expf(-(xz + gh1)));
      float n = tanhf(xn + r * gh2);
      float h2 = (1.f - z) * n + z * hl2[tid];
      hl2[tid] = h2;
      Hbuf[((long)t * 32 + b) * 1024 + m] = f2b(h2);
      float hp = __shfl_xor(h2, 1);
      if ((tid & 1) == 0) {
        unsigned pk = (unsigned)f2h(h2) | ((unsigned)f2h(hp) << 16);
        ast32(hG32 + (long)b * 512 + jc * 64 + (tid >> 1), pk);
      }
    }
    xbar(256u * (2 * t + 2));
  }
}

// ---------------- launcher ----------------

extern "C" void kernel_launch(void* const* d_in, const int* in_sizes, int n_in,
                              void* d_out, int out_size, void* d_ws, size_t ws_size,
                              hipStream_t stream) {
  const float* f    = (const float*)d_in[0];
  const float* h0   = (const float*)d_in[1];
  const float* gt   = (const float*)d_in[2];
  const float* U_w  = (const float*)d_in[4];
  const float* U_b  = (const float*)d_in[5];
  const float* V_w  = (const float*)d_in[6];
  const float* V_b  = (const float*)d_in[7];
  const float* P_w  = (const float*)d_in[8];
  const float* P_b  = (const float*)d_in[9];
  const float* W_ih = (const float*)d_in[10];
  const float* b_ih = (const float*)d_in[11];
  const float* W_hh = (const float*)d_in[12];
  const float* b_hh = (const float*)d_in[13];
  const float* dw   = (const float*)d_in[14];
  const float* db   = (const float*)d_in[15];

  char* w = (char*)d_ws;
  auto alloc = [&](size_t bytes) { char* p = w; w += (bytes + 255) & ~255ULL; return p; };

  u16*      fbf   = (u16*)alloc(4096L * 1024 * 2);
  u16*      VwB   = (u16*)alloc(256L * 1024 * 2);
  unsigned* WcatH = (unsigned*)alloc(3328L * 512 * 4);  // f16-packed [U_w; W_hh]
  u16*      WxB   = (u16*)alloc(3072L * 512 * 2);
  u16*      WmB   = (u16*)alloc(3072L * 1024 * 2);
  u16*      dwB   = (u16*)alloc(32000L * 1024 * 2);
  u16*      Xb    = (u16*)alloc(1024L * 512 * 2);
  u16*      wvfb  = (u16*)alloc(4096L * 256 * 2);
  float*    GX    = (float*)alloc(1024L * 3072 * 4);
  u16*      FWb   = (u16*)alloc(4096L * 3072 * 2);
  unsigned* hG32  = (unsigned*)alloc(32L * 512 * 4);    // f16-packed h state
  float*    gates = (float*)alloc(32L * 3328 * 4);
  u16*      Hbuf  = (u16*)alloc(1024L * 1024 * 2);
  float*    bcat  = (float*)alloc(3328L * 4);
  unsigned* cnt   = (unsigned*)alloc(256);

  auto cvg = [](long n) { long g = (n + 1023) / 1024; return (int)(g > 2048 ? 2048 : g); };

  cvt_flat<<<cvg(4194304), 256, 0, stream>>>(f, fbf, 4194304);
  cvt_flat<<<cvg(262144), 256, 0, stream>>>(V_w, VwB, 262144);
  cvt_packh<<<512, 256, 0, stream>>>(U_w, WcatH, 131072);
  cvt_packh<<<2048, 256, 0, stream>>>(W_hh, WcatH + 131072, 1572864);
  cvt_packh<<<64, 256, 0, stream>>>(h0, hG32, 16384);
  cvt_strided<<<2048, 256, 0, stream>>>(W_ih, WxB, 3072L * 512, 9, 1536, 0);
  cvt_strided<<<2048, 256, 0, stream>>>(W_ih, WmB, 3072L * 1024, 10, 1536, 512);
  cvt_flat<<<cvg(32768000), 256, 0, stream>>>(dw, dwB, 32768000);
  cvt_x<<<2048, 256, 0, stream>>>(gt, Xb);
  hipMemcpyAsync(bcat, U_b, 256 * 4, hipMemcpyDeviceToDevice, stream);
  hipMemcpyAsync(bcat + 256, b_hh, 3072 * 4, hipMemcpyDeviceToDevice, stream);
  hipMemsetAsync(cnt, 0, 4, stream);

  // loop-invariant GEMMs (bf16)
  gemm_bt<1><<<dim3(2, 32), 256, 0, stream>>>(fbf, VwB, wvfb, V_b, P_w, 4096, 256, 1024);
  gemm_bt<2><<<dim3(24, 8), 256, 0, stream>>>(Xb, WxB, GX, b_ih, nullptr, 992, 3072, 512);
  gemm_bt<0><<<dim3(24, 32), 256, 0, stream>>>(fbf, WmB, FWb, nullptr, nullptr, 4096, 3072, 1024);

  // full recurrence: persistent kernel, chunked-XCD-aligned partitions
  {
    void* ka[] = {(void*)&WcatH, (void*)&bcat, (void*)&wvfb, (void*)&FWb,
                  (void*)&GX,    (void*)&P_b,  (void*)&h0,   (void*)&hG32,
                  (void*)&gates, (void*)&Hbuf, (void*)&cnt};
    hipLaunchCooperativeKernel((void*)persist, dim3(256), dim3(1024), ka, 0, stream);
  }

  // logits
  gemm_bt<3><<<dim3(250, 8), 256, 0, stream>>>(Hbuf, dwB, (float*)d_out, db, nullptr,
                                               992, 32000, 1024);
}

// Round 15
// 826.446 us; speedup vs baseline: 3.1864x; 2.9109x over previous
//
#include <hip/hip_runtime.h>
#include <hip/hip_bf16.h>
#include <math.h>

typedef unsigned short u16;
typedef unsigned long long u64;
typedef __attribute__((ext_vector_type(8))) short short8;
typedef __attribute__((ext_vector_type(4))) float f32x4;
typedef __attribute__((ext_vector_type(2))) _Float16 half2v;

static __device__ __forceinline__ u16 f2b(float x) {
  __hip_bfloat16 h = __float2bfloat16(x);
  return *reinterpret_cast<u16*>(&h);
}
static __device__ __forceinline__ float b2f(u16 u) {
  unsigned int v = ((unsigned int)u) << 16;
  float f;
  __builtin_memcpy(&f, &v, 4);
  return f;
}
static __device__ __forceinline__ u16 f2h(float x) {
  _Float16 h = (_Float16)x;
  u16 u;
  __builtin_memcpy(&u, &h, 2);
  return u;
}
static __device__ __forceinline__ float dot2(unsigned w, unsigned h, float acc) {
  half2v a, b;
  __builtin_memcpy(&a, &w, 4);
  __builtin_memcpy(&b, &h, 4);
#if __has_builtin(__builtin_amdgcn_fdot2)
  return __builtin_amdgcn_fdot2(a, b, acc, false);
#else
  return acc + (float)a[0] * (float)b[0] + (float)a[1] * (float)b[1];
#endif
}

// agent-scope relaxed (cache-bypassing) accessors
static __device__ __forceinline__ float aldf(const float* p) {
  return __hip_atomic_load(const_cast<float*>(p), __ATOMIC_RELAXED, __HIP_MEMORY_SCOPE_AGENT);
}
static __device__ __forceinline__ void astf(float* p, float v) {
  __hip_atomic_store(p, v, __ATOMIC_RELAXED, __HIP_MEMORY_SCOPE_AGENT);
}
static __device__ __forceinline__ u64 ald8(const u64* p) {
  return __hip_atomic_load(const_cast<u64*>(p), __ATOMIC_RELAXED, __HIP_MEMORY_SCOPE_AGENT);
}
static __device__ __forceinline__ void ast32(unsigned* p, unsigned v) {
  __hip_atomic_store(p, v, __ATOMIC_RELAXED, __HIP_MEMORY_SCOPE_AGENT);
}

// ---------------- conversion kernels ----------------

__global__ void cvt_flat(const float* __restrict__ s, u16* __restrict__ d, long n) {
  long i = ((long)blockIdx.x * 256 + threadIdx.x) * 4;
  long stride = (long)gridDim.x * 1024;
  for (; i < n; i += stride) {
    float4 v = *(const float4*)(s + i);
    ushort4 o;
    o.x = f2b(v.x); o.y = f2b(v.y); o.z = f2b(v.z); o.w = f2b(v.w);
    *(ushort4*)(d + i) = o;
  }
}

// pack pairs of f32 -> u32 of 2 f16 (flat)
__global__ void cvt_packh(const float* __restrict__ s, unsigned* __restrict__ d, long npairs) {
  long i = (long)blockIdx.x * 256 + threadIdx.x;
  long step = (long)gridDim.x * 256;
  for (; i < npairs; i += step) {
    float2 v = *(const float2*)(s + 2 * i);
    d[i] = (unsigned)f2h(v.x) | ((unsigned)f2h(v.y) << 16);
  }
}

__global__ void cvt_strided(const float* __restrict__ s, u16* __restrict__ d,
                            long total, int lshift, long sstride, long soff) {
  long i = (long)blockIdx.x * 256 + threadIdx.x;
  long step = (long)gridDim.x * 256;
  long mask = (1L << lshift) - 1;
  for (; i < total; i += step) {
    long r = i >> lshift;
    long c = i & mask;
    d[i] = f2b(s[r * sstride + soff + c]);
  }
}

__global__ void cvt_x(const float* __restrict__ gt, u16* __restrict__ d) {
  long idx = (long)blockIdx.x * 256 + threadIdx.x;
  if (idx >= 1024L * 512) return;
  long m = idx >> 9;
  int k = (int)(idx & 511);
  if (m < 992) {
    int tt = (int)(m >> 5), b = (int)(m & 31);
    d[idx] = f2b(gt[((long)b * 32 + tt) * 512 + k]);
  } else {
    d[idx] = 0;
  }
}

// ---------------- generic MFMA GEMM: C = A(M,K) * B(N,K)^T ----------------
template<int EPI>
__global__ __launch_bounds__(256)
void gemm_bt(const u16* __restrict__ A, const u16* __restrict__ B,
             void* __restrict__ C0,
             const float* __restrict__ bias, const float* __restrict__ pw,
             int M, int N, int K) {
  __shared__ u16 As[4096];
  __shared__ u16 Bs[4096];
  const int tid = threadIdx.x;
  const int lane = tid & 63, wid = tid >> 6;

  int gx = gridDim.x, gy = gridDim.y;
  int orig = blockIdx.y * gx + blockIdx.x;
  int G = gx < 8 ? gx : 8;
  int ng = gx / G;
  int full = ng * G * gy;
  int ct, rt;
  if (orig < full) {
    int grp = orig / (G * gy), rem = orig % (G * gy);
    ct = grp * G + rem % G;
    rt = rem / G;
  } else {
    int Gt = gx - ng * G;
    int rem = orig - full;
    ct = ng * G + rem % Gt;
    rt = rem / Gt;
  }
  const long row0 = (long)rt * 128;
  const long col0 = (long)ct * 128;

  const int wm = (wid >> 1) * 64, wn = (wid & 1) * 64;
  const int fr = lane & 15, fq = lane >> 4;
  const int sr = wid * 16 + (lane >> 2);
  const int sc = (lane & 3) * 8;

  const u16* Ag0 = A + (row0 + sr) * (long)K + sc;
  const u16* Ag1 = Ag0 + 64 * (long)K;
  const u16* Bg0 = B + (col0 + sr) * (long)K + sc;
  const u16* Bg1 = Bg0 + 64 * (long)K;

  u16* AsW0 = &As[wid * 512];
  u16* AsW1 = &As[2048 + wid * 512];
  u16* BsW0 = &Bs[wid * 512];
  u16* BsW1 = &Bs[2048 + wid * 512];

  f32x4 acc[4][4];
#pragma unroll
  for (int i = 0; i < 4; ++i)
#pragma unroll
    for (int j = 0; j < 4; ++j) acc[i][j] = {0.f, 0.f, 0.f, 0.f};

  for (int k0 = 0; k0 < K; k0 += 32) {
    __builtin_amdgcn_global_load_lds((const __attribute__((address_space(1))) void*)(Ag0 + k0),
                                     (__attribute__((address_space(3))) void*)AsW0, 16, 0, 0);
    __builtin_amdgcn_global_load_lds((const __attribute__((address_space(1))) void*)(Ag1 + k0),
                                     (__attribute__((address_space(3))) void*)AsW1, 16, 0, 0);
    __builtin_amdgcn_global_load_lds((const __attribute__((address_space(1))) void*)(Bg0 + k0),
                                     (__attribute__((address_space(3))) void*)BsW0, 16, 0, 0);
    __builtin_amdgcn_global_load_lds((const __attribute__((address_space(1))) void*)(Bg1 + k0),
                                     (__attribute__((address_space(3))) void*)BsW1, 16, 0, 0);
    __syncthreads();
    short8 af[4], bfv[4];
#pragma unroll
    for (int i = 0; i < 4; ++i) af[i] = *(const short8*)&As[(wm + i * 16 + fr) * 32 + fq * 8];
#pragma unroll
    for (int i = 0; i < 4; ++i) bfv[i] = *(const short8*)&Bs[(wn + i * 16 + fr) * 32 + fq * 8];
#pragma unroll
    for (int i = 0; i < 4; ++i)
#pragma unroll
      for (int j = 0; j < 4; ++j)
        acc[i][j] = __builtin_amdgcn_mfma_f32_16x16x32_bf16(af[i], bfv[j], acc[i][j], 0, 0, 0);
    __syncthreads();
  }

#pragma unroll
  for (int i = 0; i < 4; ++i)
#pragma unroll
    for (int j = 0; j < 4; ++j)
#pragma unroll
      for (int q = 0; q < 4; ++q) {
        long gr = row0 + wm + i * 16 + fq * 4 + q;
        long gc = col0 + wn + j * 16 + fr;
        float v = acc[i][j][q];
        if constexpr (EPI == 0) {
          ((u16*)C0)[gr * (long)N + gc] = f2b(v);
        } else if constexpr (EPI == 1) {
          ((u16*)C0)[gr * (long)N + gc] = f2b(tanhf(v + bias[gc]) * pw[gc]);
        } else if constexpr (EPI == 2) {
          if (gr < M) ((float*)C0)[gr * (long)N + gc] = v + bias[gc];
        } else {  // EPI == 3
          if (gr < M) {
            long bb = gr & 31, tt = gr >> 5;
            float o = v + bias[gc];
            __builtin_nontemporal_store(o, &((float*)C0)[(bb * 31 + tt) * (long)N + gc]);
          }
        }
      }
}

// ---------------- persistent recurrence kernel (LDS-pinned weights) ----------------
// 256 blocks x 1024 threads, cooperative. r6/r12 relaxed barrier + fixed UC
// buffers. KEY CHANGE vs r12 (best: persist 1250 us): Wcat lives in LDS.
// Each block preloads its 52-row f16 slice (107 KB) ONCE -> per-step weight
// traffic = 0, independent of the (unknowable) blk->XCD mapping. Per-step
// phase A global traffic is just 16 KB/block of UC h reads (4 MB/step chip-
// wide, vs r12's 53 MB weights + 8 MB h).
//
// Phase A: block = (rg = blk>>2, bg = blk&3): rows [rg*52,+52) x b in
//   [bg*8,+8). Thread (akc = tid>>6, w = tid&63; bl = w&7, rch = w>>3):
//   h[bl] 64-k slice in 8 uint4 regs; 7 rows x 32 dot2 vs LDS weights
//   (wave = fixed akc: 8 distinct rows/banks x 8-way broadcast -> conflict-
//   free); partials -> plds[pair*17+akc]; 416 threads sum 16 partials,
//   UC-store gates.
// Phase B: r12 verbatim (b = blk>>3, jc = blk&7), h written f16-packed.
__global__ __launch_bounds__(1024)
void persist(const unsigned* __restrict__ WcatH, const float* __restrict__ bcat,
             const u16* __restrict__ wvfb, const u16* __restrict__ FWb,
             const float* __restrict__ GX, const float* __restrict__ pbv,
             const float* __restrict__ h0,
             unsigned* __restrict__ hG32, float* __restrict__ gates,
             u16* __restrict__ Hbuf, unsigned* __restrict__ cnt) {
  const int tid = threadIdx.x;
  const int blk = blockIdx.x;
  const int rg = blk >> 2, bg = blk & 3;   // phase A role
  const int b = blk >> 3, jc = blk & 7;    // phase B role

  __shared__ unsigned wlds[52 * 516];      // 107.3 KB: pinned f16-packed weights
  __shared__ float hl2[128];               // persistent f32 h slice (b, jc)
  __shared__ __align__(16) char smem[45056];  // phase A/B scratch union
  unsigned* hlds = (unsigned*)smem;            // [8*516] phase A
  float*    plds = (float*)(smem + 16512 * 4 / 4 + 0);  // after hlds
  // (hlds = 8*516 = 4128 u32 = 16512 B)
  plds = (float*)(smem + 16512);               // [416*17] phase A
  float* uhl   = (float*)smem;                 // [256]  phase B
  float* part  = uhl + 256;                    // [1024] phase B
  float* attnv = part + 1024;                  // [128]  phase B
  float* gmp   = attnv + 128;                  // [3*1024] phase B

  const float pb0 = pbv[0];
  if (tid < 128) hl2[tid] = h0[b * 1024 + jc * 128 + tid];

  // preload weight slice: rows [rg*52, +52), 512 u32 each -> wlds stride 516
  for (int it = tid; it < 52 * 512; it += 1024) {
    int row = it >> 9, idx = it & 511;
    wlds[row * 516 + idx] = WcatH[(long)(rg * 52 + row) * 512 + idx];
  }

  auto xbar = [&](unsigned target) {
    __syncthreads();
    if (tid == 0) {
      __hip_atomic_fetch_add(cnt, 1u, __ATOMIC_RELAXED, __HIP_MEMORY_SCOPE_AGENT);
      while (__hip_atomic_load(cnt, __ATOMIC_RELAXED, __HIP_MEMORY_SCOPE_AGENT) < target) {
        __builtin_amdgcn_s_sleep(2);
      }
    }
    __syncthreads();
  };
  xbar(256u);  // weights loaded everywhere; h0/hG32 ready

  for (int t = 0; t < 31; ++t) {
    // ===== phase A: gates GEMV from LDS weights =====
    {
      // stage 8 b's of f16-packed h: thread i loads u32[i*4 .. +4) coalesced UC
      long base = (long)(bg * 8) * 512;
      int g = tid * 4;
      u64 v0 = ald8((const u64*)(hG32 + base + g));
      u64 v1 = ald8((const u64*)(hG32 + base + g + 2));
      int bi = g >> 9, idx = g & 511;
      unsigned* dst = hlds + bi * 516 + idx;
      dst[0] = (unsigned)v0; dst[1] = (unsigned)(v0 >> 32);
      dst[2] = (unsigned)v1; dst[3] = (unsigned)(v1 >> 32);
    }
    __syncthreads();
    {
      const int akc = tid >> 6, w = tid & 63;
      const int bl = w & 7, rch = w >> 3;
      uint4 hv[8];
      const uint4* hp = (const uint4*)(hlds + bl * 516 + akc * 32);
#pragma unroll
      for (int j = 0; j < 8; ++j) hv[j] = hp[j];
#pragma unroll
      for (int i = 0; i < 7; ++i) {
        int rl = rch * 7 + i;
        if (rl < 52) {
          const uint4* wp = (const uint4*)(wlds + rl * 516 + akc * 32);
          float acc = 0.f;
#pragma unroll
          for (int j = 0; j < 8; ++j) {
            uint4 w4 = wp[j];
            acc = dot2(w4.x, hv[j].x, acc);
            acc = dot2(w4.y, hv[j].y, acc);
            acc = dot2(w4.z, hv[j].z, acc);
            acc = dot2(w4.w, hv[j].w, acc);
          }
          plds[(rl * 8 + bl) * 17 + akc] = acc;
        }
      }
    }
    __syncthreads();
    if (tid < 416) {
      const float* pp = plds + tid * 17;
      float s = 0.f;
#pragma unroll
      for (int k = 0; k < 16; ++k) s += pp[k];
      int rl = tid >> 3, bl = tid & 7;
      astf(gates + (long)(bg * 8 + bl) * 3328 + rg * 52 + rl, s);
    }
    xbar(256u * (2 * t + 2));

    // ===== phase B: attention + GRU (r12 structure) =====
    if (tid < 128) {
      u64 v = ald8((const u64*)(gates + (long)b * 3328 + tid * 2));
      float2 f2v;
      __builtin_memcpy(&f2v, &v, 8);
      uhl[tid * 2] = tanhf(f2v.x + bcat[tid * 2]);
      uhl[tid * 2 + 1] = tanhf(f2v.y + bcat[tid * 2 + 1]);
    }
    __syncthreads();
    {
      const int s = tid & 127, q = tid >> 7;  // q in 0..7, 32 dims each
      const u16* wr = wvfb + ((long)(b * 128 + s)) * 256 + q * 32;
      const float* uq = &uhl[q * 32];
      float p = 0.f;
#pragma unroll
      for (int d = 0; d < 32; d += 8) {
        short8 wv = *(const short8*)(wr + d);
#pragma unroll
        for (int e = 0; e < 8; ++e) p += b2f((u16)wv[e]) * uq[d + e];
      }
      part[tid] = p;
    }
    __syncthreads();
    if (tid < 128) {
      float s8 = pb0;
#pragma unroll
      for (int j = 0; j < 8; ++j) s8 += part[tid + 128 * j];
      attnv[tid] = s8;
    }
    __syncthreads();
    if (tid < 64) {
      float m = fmaxf(attnv[tid], attnv[tid + 64]);
#pragma unroll
      for (int o = 32; o; o >>= 1) m = fmaxf(m, __shfl_xor(m, o));
      float e0 = expf(attnv[tid] - m), e1 = expf(attnv[tid + 64] - m);
      float s2 = e0 + e1;
#pragma unroll
      for (int o = 32; o; o >>= 1) s2 += __shfl_xor(s2, o);
      float inv = 1.f / s2;
      attnv[tid] = e0 * inv;
      attnv[tid + 64] = e1 * inv;
    }
    __syncthreads();
    {
      const int ml = tid & 127, sh = tid >> 7;  // sh in 0..7, 16 s each
      const int col = jc * 128 + ml;
      float g0 = 0.f, g1 = 0.f, g2 = 0.f;
      const u16* fw = FWb + ((long)(b * 128 + sh * 16)) * 3072 + col;
#pragma unroll 4
      for (int s = 0; s < 16; ++s) {
        float a = attnv[sh * 16 + s];
        g0 += a * b2f(fw[0]);
        g1 += a * b2f(fw[1024]);
        g2 += a * b2f(fw[2048]);
        fw += 3072;
      }
      gmp[0 * 1024 + tid] = g0;
      gmp[1 * 1024 + tid] = g1;
      gmp[2 * 1024 + tid] = g2;
    }
    __syncthreads();
    if (tid < 128) {
      const int m = jc * 128 + tid;
      float gm0 = 0.f, gm1 = 0.f, gm2 = 0.f;
#pragma unroll
      for (int j = 0; j < 8; ++j) {
        gm0 += gmp[0 * 1024 + tid + 128 * j];
        gm1 += gmp[1 * 1024 + tid + 128 * j];
        gm2 += gmp[2 * 1024 + tid + 128 * j];
      }
      float gh0 = aldf(gates + (long)b * 3328 + 256 + m) + bcat[256 + m];
      float gh1 = aldf(gates + (long)b * 3328 + 1280 + m) + bcat[1280 + m];
      float gh2 = aldf(gates + (long)b * 3328 + 2304 + m) + bcat[2304 + m];
      const long gxo = ((long)t * 32 + b) * 3072;
      float xr = GX[gxo + m] + gm0;
      float xz = GX[gxo + 1024 + m] + gm1;
      float xn = GX[gxo + 2048 + m] + gm2;
      float r = 1.f / (1.f + expf(-(xr + gh0)));
      float z = 1.f / (1.f + expf(-(xz + gh1)));
      float n = tanhf(xn + r * gh2);
      float h2 = (1.f - z) * n + z * hl2[tid];
      hl2[tid] = h2;
      Hbuf[((long)t * 32 + b) * 1024 + m] = f2b(h2);
      float hp = __shfl_xor(h2, 1);
      if ((tid & 1) == 0) {
        unsigned pk = (unsigned)f2h(h2) | ((unsigned)f2h(hp) << 16);
        ast32(hG32 + (long)b * 512 + jc * 64 + (tid >> 1), pk);
      }
    }
    xbar(256u * (2 * t + 3));
  }
}

// ---------------- launcher ----------------

extern "C" void kernel_launch(void* const* d_in, const int* in_sizes, int n_in,
                              void* d_out, int out_size, void* d_ws, size_t ws_size,
                              hipStream_t stream) {
  const float* f    = (const float*)d_in[0];
  const float* h0   = (const float*)d_in[1];
  const float* gt   = (const float*)d_in[2];
  const float* U_w  = (const float*)d_in[4];
  const float* U_b  = (const float*)d_in[5];
  const float* V_w  = (const float*)d_in[6];
  const float* V_b  = (const float*)d_in[7];
  const float* P_w  = (const float*)d_in[8];
  const float* P_b  = (const float*)d_in[9];
  const float* W_ih = (const float*)d_in[10];
  const float* b_ih = (const float*)d_in[11];
  const float* W_hh = (const float*)d_in[12];
  const float* b_hh = (const float*)d_in[13];
  const float* dw   = (const float*)d_in[14];
  const float* db   = (const float*)d_in[15];

  char* w = (char*)d_ws;
  auto alloc = [&](size_t bytes) { char* p = w; w += (bytes + 255) & ~255ULL; return p; };

  u16*      fbf   = (u16*)alloc(4096L * 1024 * 2);
  u16*      VwB   = (u16*)alloc(256L * 1024 * 2);
  unsigned* WcatH = (unsigned*)alloc(3328L * 512 * 4);  // f16-packed [U_w; W_hh]
  u16*      WxB   = (u16*)alloc(3072L * 512 * 2);
  u16*      WmB   = (u16*)alloc(3072L * 1024 * 2);
  u16*      dwB   = (u16*)alloc(32000L * 1024 * 2);
  u16*      Xb    = (u16*)alloc(1024L * 512 * 2);
  u16*      wvfb  = (u16*)alloc(4096L * 256 * 2);
  float*    GX    = (float*)alloc(1024L * 3072 * 4);
  u16*      FWb   = (u16*)alloc(4096L * 3072 * 2);
  unsigned* hG32  = (unsigned*)alloc(32L * 512 * 4);    // f16-packed h state
  float*    gates = (float*)alloc(32L * 3328 * 4);
  u16*      Hbuf  = (u16*)alloc(1024L * 1024 * 2);
  float*    bcat  = (float*)alloc(3328L * 4);
  unsigned* cnt   = (unsigned*)alloc(256);

  auto cvg = [](long n) { long g = (n + 1023) / 1024; return (int)(g > 2048 ? 2048 : g); };

  cvt_flat<<<cvg(4194304), 256, 0, stream>>>(f, fbf, 4194304);
  cvt_flat<<<cvg(262144), 256, 0, stream>>>(V_w, VwB, 262144);
  cvt_packh<<<512, 256, 0, stream>>>(U_w, WcatH, 131072);
  cvt_packh<<<2048, 256, 0, stream>>>(W_hh, WcatH + 131072, 1572864);
  cvt_packh<<<64, 256, 0, stream>>>(h0, hG32, 16384);
  cvt_strided<<<2048, 256, 0, stream>>>(W_ih, WxB, 3072L * 512, 9, 1536, 0);
  cvt_strided<<<2048, 256, 0, stream>>>(W_ih, WmB, 3072L * 1024, 10, 1536, 512);
  cvt_flat<<<cvg(32768000), 256, 0, stream>>>(dw, dwB, 32768000);
  cvt_x<<<2048, 256, 0, stream>>>(gt, Xb);
  hipMemcpyAsync(bcat, U_b, 256 * 4, hipMemcpyDeviceToDevice, stream);
  hipMemcpyAsync(bcat + 256, b_hh, 3072 * 4, hipMemcpyDeviceToDevice, stream);
  hipMemsetAsync(cnt, 0, 4, stream);

  // loop-invariant GEMMs (bf16)
  gemm_bt<1><<<dim3(2, 32), 256, 0, stream>>>(fbf, VwB, wvfb, V_b, P_w, 4096, 256, 1024);
  gemm_bt<2><<<dim3(24, 8), 256, 0, stream>>>(Xb, WxB, GX, b_ih, nullptr, 992, 3072, 512);
  gemm_bt<0><<<dim3(24, 32), 256, 0, stream>>>(fbf, WmB, FWb, nullptr, nullptr, 4096, 3072, 1024);

  // full recurrence: persistent kernel, LDS-pinned gate weights
  {
    void* ka[] = {(void*)&WcatH, (void*)&bcat, (void*)&wvfb, (void*)&FWb,
                  (void*)&GX,    (void*)&P_b,  (void*)&h0,   (void*)&hG32,
                  (void*)&gates, (void*)&Hbuf, (void*)&cnt};
    hipLaunchCooperativeKernel((void*)persist, dim3(256), dim3(1024), ka, 0, stream);
  }

  // logits
  gemm_bt<3><<<dim3(250, 8), 256, 0, stream>>>(Hbuf, dwB, (float*)d_out, db, nullptr,
                                               992, 32000, 1024);
}